// Round 10
// baseline (152.141 us; speedup 1.0000x reference)
//
#include <hip/hip_runtime.h>

#define DD 160
#define HH 192
#define WW 160
#define HWs (HH * WW)          // 30720
#define NTOT 9830400.0f        // 2*160*192*160
#define DOUT 20                // output slices per block
#define NIT  28                // DOUT + 8 halo
#define NBLK 960

#define SDS 11                 // SD row stride (h4 units)
#define SDC 266                // SD channel stride; 266 mod 16 = 10 (bank-audited)
#define SDP (5 * SDC)          // 1330
#define HSS 11                 // HS row stride
#define HSC 186                // HS channel stride; mod 16 = 10
#define HSP (5 * HSC)          // 930

typedef float    v4 __attribute__((ext_vector_type(4)));
typedef _Float16 h4 __attribute__((ext_vector_type(4)));

__device__ __forceinline__ void block_sync_lds() {
    __builtin_amdgcn_s_waitcnt(0xc07f);   // lgkmcnt(0) only; vmem stays in flight
    __builtin_amdgcn_s_barrier();
}
__device__ __forceinline__ v4 up(h4 x) { return __builtin_convertvector(x, v4); }
__device__ __forceinline__ h4 dn(v4 x) { return __builtin_convertvector(x, h4); }

// Fully-fused NCC, D-first, 1 barrier/iter, depth-3 phase pipeline + depth-2
// global prefetch. Per iter t:
//  ph1(t)   rt<240       : fp16-packed delta products, fp32 rolling D-sums,
//                          write 5 fp16 SD -> SD[t&1]; rotate pA<-pB, load pB
//                          (consumed 2 iters later -> ~3000cyc latency cover)
//  ph3(t-2) rt in[64,192): 128 tasks (hh,e): 3 h4/ch reads of HS[t&1],
//                          W-slide 4 outputs + cc. Conflict-free (11hh mod 16
//                          bijective, +e distinct).
//  ph2(t-1) rt in[192,242): 50 tasks (c,g): single-pass 24-row rolling H-sum
//                          over SD[(t-1)&1] (9-reg window, each row read ONCE),
//                          16 fp16 writes -> HS[(t-1)&1].
// Parity audit as round 9 (all RAW/WAR pairs barrier-separated). Bank audit:
// ph2 reads/writes lanes ≡ {10c+g} mod 16 -> each 16-lane phase covers
// distinct pairs; ph1 writes {11r+g} (1 collision/phase); ph3 {11hh+e} clean.
// LDS 37.2 KB -> 4 blocks/CU.
__global__ __launch_bounds__(256, 4) void kf(const float* __restrict__ I,
                                             const float* __restrict__ J,
                                             float* __restrict__ partial) {
    __shared__ h4    SDL[2 * SDP];   // 21280 B
    __shared__ h4    HSL[2 * HSP];   // 14880 B
    __shared__ float red[256];

    const int tid = threadIdx.x;
    const int bx = blockIdx.x, by = blockIdx.y, b = blockIdx.z;
    const int w0 = (bx % 5) * 32, h0 = (bx / 5) * 16;
    const int d0 = by * DOUT;
    const int bid = bx + 60 * (by + 8 * b);

    const int rt = tid ^ ((bx & 1) << 7);   // alternate heavy-wave SIMDs

    // ---- ph1: 240 columns = 24 rows x 10 f4-cols
    const bool p1 = rt < 240;
    const int r = rt / 10, g = rt % 10;
    const int gh = h0 - 4 + r, gw = w0 - 4 + g * 4;
    const bool colOK = p1 && gh >= 0 && gh < HH && gw >= 0 && gw < WW;
    const size_t colOff = (size_t)gh * WW + gw;
    const float* Ib = I + (size_t)b * DD * HWs + colOff;
    const float* Jb = J + (size_t)b * DD * HWs + colOff;
    h4* const sdw = &SDL[r * SDS + g];

    // ---- ph3: 128 tasks = 16 h-rows x 8 4-output segments
    const bool p3 = (rt >= 64) && (rt < 192);
    const int q3 = rt - 64;
    const int hh = q3 & 15, e3 = q3 >> 4;
    const int hsrOff = hh * HSS + e3;

    // ---- ph2: 50 tasks = 5 ch x 10 f4-cols, single-pass over 24 rows
    const bool p2 = (rt >= 192) && (rt < 242);
    const int u2 = rt - 192;
    const int c2 = u2 / 10, g2 = u2 % 10;
    const int sdrOff = c2 * SDC + g2;
    const int hswOff = c2 * HSC + g2;

    v4 sd0 = 0.f, sd1 = 0.f, sd2 = 0.f, sd3 = 0.f, sd4 = 0.f;
    h4 fI[9], fJ[9];
#pragma unroll
    for (int u = 0; u < 9; ++u) { fI[u] = (h4)(_Float16)0; fJ[u] = (h4)(_Float16)0; }

    // depth-2 prefetch: pA consumed this iter (loaded 2 iters ago), pB in flight
    v4 pAI = 0.f, pAJ = 0.f, pBI = 0.f, pBJ = 0.f;
    {
        const int s0 = d0 - 4;
        if (colOK && s0 >= 0) {
            pAI = *(const v4*)(Ib + (size_t)s0 * HWs);
            pAJ = *(const v4*)(Jb + (size_t)s0 * HWs);
        }
        const int s1 = d0 - 3;
        if (colOK && s1 >= 0) {
            pBI = *(const v4*)(Ib + (size_t)s1 * HWs);
            pBJ = *(const v4*)(Jb + (size_t)s1 * HWs);
        }
    }

    float acc = 0.f;
    const float inv = 1.0f / 729.0f;

    for (int tb = 0; tb < 36; tb += 9) {
#pragma unroll
        for (int u = 0; u < 9; ++u) {
            const int t = tb + u;
            if (t < NIT + 2) {
                // ---------- ph1(t)
                if (t < NIT && p1) {
                    h4 cI = dn(pAI), cJ = dn(pAJ);   // vmcnt waits pA only
                    h4 dI = cI, dJ = cJ;
                    h4 dII = cI * cI, dJJ = cJ * cJ, dIJ = cI * cJ;
                    if (t >= 9) {
                        h4 oI = fI[u], oJ = fJ[u];
                        dI -= oI; dJ -= oJ;
                        dII -= oI * oI; dJJ -= oJ * oJ; dIJ -= oI * oJ;
                    }
                    fI[u] = cI; fJ[u] = cJ;
                    sd0 += up(dI); sd1 += up(dJ); sd2 += up(dII);
                    sd3 += up(dJJ); sd4 += up(dIJ);
                    h4* const sdq = sdw + (t & 1) * SDP;
                    sdq[0]       = dn(sd0);
                    sdq[SDC]     = dn(sd1);
                    sdq[2 * SDC] = dn(sd2);
                    sdq[3 * SDC] = dn(sd3);
                    sdq[4 * SDC] = dn(sd4);
                    // rotate + issue load for slice si+2 (consumed at t+2)
                    pAI = pBI; pAJ = pBJ;
                    pBI = 0.f; pBJ = 0.f;
                    const int sn = d0 - 2 + t;
                    if (t + 2 < NIT && colOK && sn >= 0 && sn < DD) {
                        pBI = *(const v4*)(Ib + (size_t)sn * HWs);
                        pBJ = *(const v4*)(Jb + (size_t)sn * HWs);
                    }
                }

                // ---------- ph3(t-2): W-slide + cc (output depth d0+t-10)
                if (t >= 10 && p3) {
                    const h4* const hsr = &HSL[(t & 1) * HSP + hsrOff];
                    float w[5][4];
#pragma unroll
                    for (int c = 0; c < 5; ++c) {
                        v4 fa = up(hsr[c * HSC]);
                        v4 fb = up(hsr[c * HSC + 1]);
                        v4 fc = up(hsr[c * HSC + 2]);
                        float s = fa[0] + fa[1] + fa[2] + fa[3] +
                                  fb[0] + fb[1] + fb[2] + fb[3] + fc[0];
                        w[c][0] = s;
                        s += fc[1] - fa[0]; w[c][1] = s;
                        s += fc[2] - fa[1]; w[c][2] = s;
                        s += fc[3] - fa[2]; w[c][3] = s;
                    }
#pragma unroll
                    for (int e = 0; e < 4; ++e) {
                        float mu1 = w[0][e] * inv, mu2 = w[1][e] * inv;
                        float g1  = fmaf(-mu1, mu1, w[2][e] * inv);
                        float g2v = fmaf(-mu2, mu2, w[3][e] * inv);
                        float g12 = fmaf(-mu1, mu2, w[4][e] * inv);
                        acc += __fdividef(g12 * g12, fmaf(g1, g2v, 1e-5f));
                    }
                }

                // ---------- ph2(t-1): single-pass rolling H-sum (reads 1x)
                if (t >= 1 && t <= NIT && p2) {
                    const int par = (t - 1) & 1;
                    const h4* const sdr = &SDL[par * SDP + sdrOff];
                    h4* const hsw = &HSL[par * HSP + hswOff];
                    h4 win[9];
                    h4 s;
                    win[0] = sdr[0]; s = win[0];
#pragma unroll
                    for (int k = 1; k < 9; ++k) {
                        win[k] = sdr[k * SDS];
                        s += win[k];
                    }
                    hsw[0] = s;
#pragma unroll
                    for (int j = 1; j < 16; ++j) {
                        h4 nv = sdr[(j + 8) * SDS];
                        const int slot = (j - 1) % 9;
                        s += nv - win[slot];
                        win[slot] = nv;
                        hsw[j * HSS] = s;
                    }
                }

                block_sync_lds();
            }
        }
    }

    red[tid] = acc;     // only ph3 lanes nonzero
    __syncthreads();
    if (tid < 128) red[tid] += red[tid + 128];
    __syncthreads();
    if (tid < 64) {
        float a = red[tid] + red[tid + 64];
#pragma unroll
        for (int off = 32; off > 0; off >>= 1) a += __shfl_down(a, off);
        if (tid == 0) partial[bid] = a;
    }
}

__global__ void k3_final(const float* __restrict__ partial,
                         float* __restrict__ out) {
    __shared__ float r[1024];
    const int i = threadIdx.x;
    r[i] = (i < NBLK) ? partial[i] : 0.f;
    __syncthreads();
    for (int off = 512; off > 0; off >>= 1) {
        if (i < off) r[i] += r[i + off];
        __syncthreads();
    }
    if (i == 0) out[0] = -r[0] * (1.0f / NTOT);
}

extern "C" void kernel_launch(void* const* d_in, const int* in_sizes, int n_in,
                              void* d_out, int out_size, void* d_ws, size_t ws_size,
                              hipStream_t stream) {
    (void)in_sizes; (void)n_in; (void)out_size; (void)ws_size;
    const float* I = (const float*)d_in[0];   // y_true
    const float* J = (const float*)d_in[1];   // y_pred
    float* out     = (float*)d_out;
    float* partial = (float*)d_ws;            // NBLK floats, all written

    dim3 grid(60, 8, 2);                      // (5w x 12h tiles, D/20, B)
    kf<<<grid, 256, 0, stream>>>(I, J, partial);
    k3_final<<<1, 1024, 0, stream>>>(partial, out);
}